// Round 11
// baseline (837.575 us; speedup 1.0000x reference)
//
#include <hip/hip_runtime.h>
#include <hip/hip_bf16.h>
#include <math.h>

// Problem constants (match reference)
#define BB 8
#define SS 2048
#define DD 1024
#define DS 64
#define MM (BB*SS)   // 16384

// ---------------- helpers ----------------

__device__ __forceinline__ float4 ld4(const float* p) { return *(const float4*)p; }

template<int CTRL>
__device__ __forceinline__ float dppadd(float x) {
  int v = __builtin_amdgcn_update_dpp(0, __float_as_int(x), CTRL, 0xf, 0xf, true);
  return x + __int_as_float(v);
}

__device__ __forceinline__ float xor16add(float x) {
#if defined(__has_builtin) && __has_builtin(__builtin_amdgcn_permlane16_swap)
  auto r = __builtin_amdgcn_permlane16_swap(__float_as_uint(x), __float_as_uint(x), false, false);
  return __uint_as_float(r[0]) + __uint_as_float(r[1]);
#else
  return x + __shfl_xor(x, 16, 64);
#endif
}
__device__ __forceinline__ float xor32add(float x) {
#if defined(__has_builtin) && __has_builtin(__builtin_amdgcn_permlane32_swap)
  auto r = __builtin_amdgcn_permlane32_swap(__float_as_uint(x), __float_as_uint(x), false, false);
  return __uint_as_float(r[0]) + __uint_as_float(r[1]);
#else
  return x + __shfl_xor(x, 32, 64);
#endif
}

// full 64-lane butterfly sum; result valid in all lanes
__device__ __forceinline__ float wsum(float x) {
  x = dppadd<0xB1>(x);
  x = dppadd<0x4E>(x);
  x = dppadd<0x141>(x);
  x = dppadd<0x140>(x);
  x = xor16add(x);
  x = xor32add(x);
  return x;
}

__device__ __forceinline__ float gelu_exact(float x) {
  return 0.5f * x * (1.f + erff(x * 0.7071067811865476f));
}

// ---------------- k0: pack weights [Wk;Wv;Wq;ir_w1;pw;0-pad] -> Wcat[320][1024]
__global__ __launch_bounds__(256) void pack_w(
    const float* __restrict__ Wk, const float* __restrict__ Wv,
    const float* __restrict__ Wq, const float* __restrict__ ir_w1,
    const float* __restrict__ pw, float* __restrict__ Wcat) {
  int idx = blockIdx.x * 256 + threadIdx.x;   // 320*1024 total
  int r = idx >> 10, c = idx & 1023;
  float val = 0.f;
  if (r < 64)       val = Wk[r*1024 + c];
  else if (r < 128) val = Wv[(r-64)*1024 + c];
  else if (r < 192) val = Wq[(r-128)*1024 + c];
  else if (r < 256) val = ir_w1[(r-192)*1024 + c];
  else if (r < 259) val = pw[(r-256)*1024 + c];
  Wcat[idx] = val;
}

// ---------------- k1: Y[16384][320] = X[16384][1024] @ Wcat[320][1024]^T
__global__ __launch_bounds__(256) void gemm1(
    const float* __restrict__ X, const float* __restrict__ Wcat,
    float* __restrict__ Y) {
  __shared__ float As[32*128];   // [k][m]
  __shared__ float Bs[32*64];    // [k][n]
  const int t  = threadIdx.x;
  const int m0 = blockIdx.x * 128;
  const int n0 = blockIdx.y * 64;
  const int mi = t >> 4, ni = t & 15;
  const int rA = t >> 1, hA = t & 1;
  const int rB = t >> 2, qB = t & 3;
  float acc[8][4];
  #pragma unroll
  for (int i = 0; i < 8; ++i)
    #pragma unroll
    for (int j = 0; j < 4; ++j) acc[i][j] = 0.f;

  for (int k0 = 0; k0 < 1024; k0 += 32) {
    __syncthreads();
    {
      const float* src = X + (size_t)(m0 + rA)*1024 + k0 + hA*16;
      #pragma unroll
      for (int jj = 0; jj < 4; ++jj) {
        float4 xv = ld4(src + jj*4);
        int kk = hA*16 + jj*4;
        As[(kk+0)*128 + rA] = xv.x; As[(kk+1)*128 + rA] = xv.y;
        As[(kk+2)*128 + rA] = xv.z; As[(kk+3)*128 + rA] = xv.w;
      }
      const float* srcB = Wcat + (size_t)(n0 + rB)*1024 + k0 + qB*8;
      #pragma unroll
      for (int jj = 0; jj < 2; ++jj) {
        float4 bv = ld4(srcB + jj*4);
        int kb = qB*8 + jj*4;
        Bs[(kb+0)*64 + rB] = bv.x; Bs[(kb+1)*64 + rB] = bv.y;
        Bs[(kb+2)*64 + rB] = bv.z; Bs[(kb+3)*64 + rB] = bv.w;
      }
    }
    __syncthreads();
    #pragma unroll
    for (int kk = 0; kk < 32; ++kk) {
      float a[8], bv[4];
      float4 a0 = *(const float4*)&As[kk*128 + mi*8];
      float4 a1 = *(const float4*)&As[kk*128 + mi*8 + 4];
      float4 b0 = *(const float4*)&Bs[kk*64 + ni*4];
      a[0]=a0.x; a[1]=a0.y; a[2]=a0.z; a[3]=a0.w;
      a[4]=a1.x; a[5]=a1.y; a[6]=a1.z; a[7]=a1.w;
      bv[0]=b0.x; bv[1]=b0.y; bv[2]=b0.z; bv[3]=b0.w;
      #pragma unroll
      for (int im = 0; im < 8; ++im)
        #pragma unroll
        for (int in = 0; in < 4; ++in)
          acc[im][in] = fmaf(a[im], bv[in], acc[im][in]);
    }
  }
  #pragma unroll
  for (int im = 0; im < 8; ++im) {
    float4 o; o.x = acc[im][0]; o.y = acc[im][1]; o.z = acc[im][2]; o.w = acc[im][3];
    *(float4*)&Y[(size_t)(m0 + mi*8 + im)*320 + n0 + ni*4] = o;
  }
}

// ---------------- k2: per-token postprocess -> K,V,Q,NU,PW, SCL8[0..3]
__global__ __launch_bounds__(256) void post_kernel(
    const float* __restrict__ Y,
    const float* __restrict__ nm_w1, const float* __restrict__ nm_b1,
    const float* __restrict__ nm_w2, const float* __restrict__ nm_b2,
    const float* __restrict__ ir_b1, const float* __restrict__ ir_w2,
    const float* __restrict__ ir_b2, const float* __restrict__ sap,
    float* __restrict__ K, float* __restrict__ V, float* __restrict__ Q,
    float* __restrict__ NU, float* __restrict__ PW,
    float* __restrict__ SCL8) {
  __shared__ float w1s[128*65];
  __shared__ float w2s[64*129];
  __shared__ float vbuf[4][64];
  __shared__ float h1buf[4][128];
  const int tid = threadIdx.x, wid = tid >> 6, l = tid & 63;
  for (int i = tid; i < 128*64; i += 256) w1s[(i>>6)*65 + (i&63)]  = nm_w1[i];
  for (int i = tid; i < 64*128; i += 256) w2s[(i>>7)*129 + (i&127)] = nm_w2[i];
  __syncthreads();
  const float sa   = *sap;
  const float b1a  = nm_b1[l], b1b = nm_b1[64+l], b2l = nm_b2[l];
  const float irb1 = ir_b1[l], irw2 = ir_w2[l],  irb2 = ir_b2[0];
  for (int r = 0; r < 4; ++r) {
    const int tok = blockIdx.x*16 + r*4 + wid;
    const float* yr = Y + (size_t)tok*320;
    float kr = yr[l], vr = yr[64+l], qr = yr[128+l], hr = yr[192+l];
    float rk = 1.f / fmaxf(sqrtf(wsum(kr*kr)), 1e-12f);
    float rq = 1.f / fmaxf(sqrtf(wsum(qr*qr)), 1e-12f);
    float kn = kr*rk, qn = qr*rq;
    float qk = wsum(kn*qn);
    float g  = gelu_exact(hr + irb1);
    float logit = wsum(g*irw2) + irb2;
    float imp = 1.f/(1.f+expf(-logit));
    float bs  = (imp > 0.5f) ? (1.f - sa) : 0.f;   // (1-slow_alpha)*u_slow
    K[(size_t)tok*64+l] = kn; V[(size_t)tok*64+l] = vr; Q[(size_t)tok*64+l] = qn;
    vbuf[wid][l] = vr;
    __syncthreads();
    float h1a = b1a, h1b = b1b;
    #pragma unroll 8
    for (int c = 0; c < 64; ++c) {
      float vv = vbuf[wid][c];
      h1a = fmaf(w1s[l*65 + c], vv, h1a);
      h1b = fmaf(w1s[(64+l)*65 + c], vv, h1b);
    }
    h1buf[wid][l]    = gelu_exact(h1a);
    h1buf[wid][64+l] = gelu_exact(h1b);
    __syncthreads();
    float nu = b2l;
    #pragma unroll 8
    for (int j = 0; j < 128; ++j) nu = fmaf(w2s[l*129 + j], h1buf[wid][j], nu);
    NU[(size_t)tok*64+l] = nu;
    float p0 = yr[256], p1 = yr[257], p2 = yr[258];
    float mx = fmaxf(p0, fmaxf(p1, p2));
    float e0 = expf(p0-mx), e1 = expf(p1-mx), e2 = expf(p2-mx);
    float inv = 1.f/(e0+e1+e2);
    if (l == 0) {
      PW[(size_t)tok*3]   = e0*inv;
      float4 s; s.x = qk; s.y = bs; s.z = e0*inv; s.w = e1*inv;
      *(float4*)&SCL8[(size_t)tok*8] = s;
    }
    else if (l == 1)   PW[(size_t)tok*3+1] = e1*inv;
    else if (l == 2)   PW[(size_t)tok*3+2] = e2*inv;
    __syncthreads();
  }
}

// ---------------- k2c: per-chunk dot matrices for ALL (b,c) in parallel.
// AKK[ch][t][j] = k_t.k_j, AQK[ch][t][j] = q_t.k_j  (t,j chunk-local 0..63)
__global__ __launch_bounds__(256) void chunkdots(
    const float* __restrict__ K, const float* __restrict__ Q,
    float* __restrict__ AKK, float* __restrict__ AQK) {
  __shared__ float Kl[64*68], Ql[64*68];
  const int tid = threadIdx.x;
  const size_t base = (size_t)blockIdx.x * 4096;   // chunk = b*32+c; 64 tokens x 64
  #pragma unroll
  for (int it = 0; it < 4; ++it) {
    int idx4 = (tid + it*256)*4; int r = idx4 >> 6; int d = idx4 & 63;
    *(float4*)&Kl[r*68+d] = ld4(&K[base + r*64 + d]);
    *(float4*)&Ql[r*68+d] = ld4(&Q[base + r*64 + d]);
  }
  __syncthreads();
  const int t0 = (tid >> 4) * 4, j0 = (tid & 15) * 4;
  float akk[4][4], aqk[4][4];
  #pragma unroll
  for (int i = 0; i < 4; ++i)
    #pragma unroll
    for (int j = 0; j < 4; ++j) { akk[i][j] = 0.f; aqk[i][j] = 0.f; }
  for (int d = 0; d < 64; ++d) {
    float kt[4], qt[4], kj[4];
    #pragma unroll
    for (int i = 0; i < 4; ++i) {
      kt[i] = Kl[(t0+i)*68 + d];
      qt[i] = Ql[(t0+i)*68 + d];
      kj[i] = Kl[(j0+i)*68 + d];
    }
    #pragma unroll
    for (int i = 0; i < 4; ++i)
      #pragma unroll
      for (int j = 0; j < 4; ++j) {
        akk[i][j] = fmaf(kt[i], kj[j], akk[i][j]);
        aqk[i][j] = fmaf(qt[i], kj[j], aqk[i][j]);
      }
  }
  #pragma unroll
  for (int i = 0; i < 4; ++i) {
    float4 a; a.x=akk[i][0]; a.y=akk[i][1]; a.z=akk[i][2]; a.w=akk[i][3];
    float4 b; b.x=aqk[i][0]; b.y=aqk[i][1]; b.z=aqk[i][2]; b.w=aqk[i][3];
    *(float4*)&AKK[base + (t0+i)*64 + j0] = a;
    *(float4*)&AQK[base + (t0+i)*64 + j0] = b;
  }
}

// ---------------- k3: chunked UT-transform scan.
// Grid: 32 blocks = 8 batches x 4 v-splits (16 v-cols each), 256 threads.
// Per chunk (C=64): U solve (I + (1-fa)M)U = (1-fa)(V - d.BFK) via blocked
// forward substitution (8 sub-blocks of 8), gated slow path identically,
// then pq/pqs/output GEMMs and state update. States F,S live in LDS.
__global__ __launch_bounds__(256) void scan_chunked(
    const float* __restrict__ K, const float* __restrict__ Q,
    const float* __restrict__ V, const float* __restrict__ SCL8,
    const float* __restrict__ AKK, const float* __restrict__ AQK,
    const float* __restrict__ fap, const float* __restrict__ sap,
    float* __restrict__ OBASE, float* __restrict__ E2) {
  __shared__ float Kc[64*68];          // K chunk [t][d], stride 68
  __shared__ float Bc[64*68];          // Qc -> Akk -> Aqk (reused)
  __shared__ float Fs[64*16], Ssl[64*16];   // state slices [kd][v]
  __shared__ float Uu[64*16], Uss[64*16];   // RHS -> solved U / Us
  __shared__ float BFQ[64*16], BSQ[64*16];  // F0^T q_t, S0^T q_t slices
  __shared__ float scal[64*4];
  __shared__ float fapow[65], sapow[65];
  const int b   = blockIdx.x >> 2;
  const int vs0 = (blockIdx.x & 3) * 16;
  const int tid = threadIdx.x;
  const int t   = tid >> 2;            // row 0..63
  const int vq  = (tid & 3) * 4;       // 0,4,8,12 within slice
  const float fa = *fap, sa = *sap, omfa = 1.f - fa;
  if (tid == 0) {
    float f = 1.f, s = 1.f;
    for (int n = 0; n <= 64; ++n) { fapow[n] = f; sapow[n] = s; f *= fa; s *= sa; }
  }
  #pragma unroll
  for (int i = 0; i < 4; ++i) { Fs[tid*4+i] = 0.f; Ssl[tid*4+i] = 0.f; }
  __syncthreads();

  const size_t tb = (size_t)b * SS;    // global token base for batch
  float vreg[4];

#define STAGE68(dst, srcp) { _Pragma("unroll")                        \
    for (int it = 0; it < 4; ++it) {                                  \
      int idx4 = (tid + it*256)*4; int r = idx4 >> 6; int d = idx4 & 63; \
      *(float4*)&dst[r*68+d] = ld4(&(srcp)[r*64 + d]); } }

  for (int c = 0; c < 32; ++c) {
    const size_t tok0 = tb + (size_t)c*64;
    const size_t ch   = (size_t)(b*32 + c) * 4096;
    // ---- P0: stage Kc, Qc, scalars
    STAGE68(Kc, K + tok0*64)
    STAGE68(Bc, Q + tok0*64)
    { int tt2 = tid >> 2, f = tid & 3;
      scal[tid] = SCL8[(tok0 + tt2)*8 + f]; }
    __syncthreads();

    // ---- P1: 4 state projections + RHS build
    {
      float aFK[4] = {0,0,0,0}, aFQ[4] = {0,0,0,0};
      float aSK[4] = {0,0,0,0}, aSQ[4] = {0,0,0,0};
      #pragma unroll 8
      for (int kd = 0; kd < 64; ++kd) {
        float kt = Kc[t*68 + kd];
        float qt = Bc[t*68 + kd];
        float4 fv = *(const float4*)&Fs[kd*16 + vq];
        float4 sv = *(const float4*)&Ssl[kd*16 + vq];
        aFK[0]=fmaf(kt,fv.x,aFK[0]); aFK[1]=fmaf(kt,fv.y,aFK[1]);
        aFK[2]=fmaf(kt,fv.z,aFK[2]); aFK[3]=fmaf(kt,fv.w,aFK[3]);
        aFQ[0]=fmaf(qt,fv.x,aFQ[0]); aFQ[1]=fmaf(qt,fv.y,aFQ[1]);
        aFQ[2]=fmaf(qt,fv.z,aFQ[2]); aFQ[3]=fmaf(qt,fv.w,aFQ[3]);
        aSK[0]=fmaf(kt,sv.x,aSK[0]); aSK[1]=fmaf(kt,sv.y,aSK[1]);
        aSK[2]=fmaf(kt,sv.z,aSK[2]); aSK[3]=fmaf(kt,sv.w,aSK[3]);
        aSQ[0]=fmaf(qt,sv.x,aSQ[0]); aSQ[1]=fmaf(qt,sv.y,aSQ[1]);
        aSQ[2]=fmaf(qt,sv.z,aSQ[2]); aSQ[3]=fmaf(qt,sv.w,aSQ[3]);
      }
      float4 vg = ld4(&V[(tok0 + t)*64 + vs0 + vq]);
      vreg[0]=vg.x; vreg[1]=vg.y; vreg[2]=vg.z; vreg[3]=vg.w;
      const float bs = scal[t*4+1];
      const float dft = fapow[t], dst_ = sapow[t];
      #pragma unroll
      for (int i = 0; i < 4; ++i) {
        Uu [t*16+vq+i] = omfa*(vreg[i] - dft *aFK[i]);
        Uss[t*16+vq+i] = bs  *(vreg[i] - dst_*aSK[i]);
        BFQ[t*16+vq+i] = aFQ[i];
        BSQ[t*16+vq+i] = aSQ[i];
      }
    }
    __syncthreads();
    // ---- stage Akk into Bc
    STAGE68(Bc, AKK + ch)
    __syncthreads();

    // ---- P3: blocked double forward substitution
    #pragma unroll 1
    for (int I = 0; I < 8; ++I) {
      const int I8 = I*8;
      // (a) in-block solves: wave0 -> U, wave1 -> Us (lanes 0..15 active)
      if (tid < 64) {
        const int v = tid;
        if (v < 16) {
          float ureg[8];
          #pragma unroll
          for (int r = 0; r < 8; ++r) {
            const int ttq = I8 + r;
            float x = Uu[ttq*16 + v];
            #pragma unroll
            for (int jj = 0; jj < r; ++jj) {
              float coef = omfa * fapow[r-1-jj] * Bc[ttq*68 + I8+jj];
              x = fmaf(-coef, ureg[jj], x);
            }
            ureg[r] = x;
            Uu[ttq*16 + v] = x;
          }
        }
      } else if (tid < 128) {
        const int v = tid - 64;
        if (v < 16) {
          float ureg[8];
          #pragma unroll
          for (int r = 0; r < 8; ++r) {
            const int ttq = I8 + r;
            const float bs = scal[ttq*4+1];
            float x = Uss[ttq*16 + v];
            #pragma unroll
            for (int jj = 0; jj < r; ++jj) {
              float coef = bs * sapow[r-1-jj] * Bc[ttq*68 + I8+jj];
              x = fmaf(-coef, ureg[jj], x);
            }
            ureg[r] = x;
            Uss[ttq*16 + v] = x;
          }
        }
      }
      __syncthreads();
      // (b) rank-8 update of remaining rows
      if (I < 7 && t >= I8 + 8) {
        float xu[4], xs[4];
        #pragma unroll
        for (int i = 0; i < 4; ++i) { xu[i] = Uu[t*16+vq+i]; xs[i] = Uss[t*16+vq+i]; }
        const float bs = scal[t*4+1];
        #pragma unroll
        for (int jj = 0; jj < 8; ++jj) {
          const int j = I8 + jj;
          const float akv = Bc[t*68 + j];
          const float cf = omfa * fapow[t-1-j] * akv;
          const float cs = bs   * sapow[t-1-j] * akv;
          float4 uj  = *(const float4*)&Uu [j*16+vq];
          float4 usj = *(const float4*)&Uss[j*16+vq];
          xu[0]=fmaf(-cf,uj.x,xu[0]); xu[1]=fmaf(-cf,uj.y,xu[1]);
          xu[2]=fmaf(-cf,uj.z,xu[2]); xu[3]=fmaf(-cf,uj.w,xu[3]);
          xs[0]=fmaf(-cs,usj.x,xs[0]); xs[1]=fmaf(-cs,usj.y,xs[1]);
          xs[2]=fmaf(-cs,usj.z,xs[2]); xs[3]=fmaf(-cs,usj.w,xs[3]);
        }
        #pragma unroll
        for (int i = 0; i < 4; ++i) { Uu[t*16+vq+i] = xu[i]; Uss[t*16+vq+i] = xs[i]; }
      }
      __syncthreads();
    }

    // ---- stage Aqk into Bc
    STAGE68(Bc, AQK + ch)
    __syncthreads();

    // ---- P4: outputs (pq, pqs, o_base, e) + P5: state update
    {
      float pq[4], pqs[4];
      const float dft = fapow[t], dst_ = sapow[t];
      #pragma unroll
      for (int i = 0; i < 4; ++i) {
        pq[i]  = dft  * BFQ[t*16+vq+i];
        pqs[i] = dst_ * BSQ[t*16+vq+i];
      }
      for (int j = 0; j < t; ++j) {
        const float aq = Bc[t*68 + j];
        const float cf = fapow[t-1-j] * aq;
        const float cs = sapow[t-1-j] * aq;
        float4 uj  = *(const float4*)&Uu [j*16+vq];
        float4 usj = *(const float4*)&Uss[j*16+vq];
        pq[0]=fmaf(cf,uj.x,pq[0]);  pq[1]=fmaf(cf,uj.y,pq[1]);
        pq[2]=fmaf(cf,uj.z,pq[2]);  pq[3]=fmaf(cf,uj.w,pq[3]);
        pqs[0]=fmaf(cs,usj.x,pqs[0]); pqs[1]=fmaf(cs,usj.y,pqs[1]);
        pqs[2]=fmaf(cs,usj.z,pqs[2]); pqs[3]=fmaf(cs,usj.w,pqs[3]);
      }
      const float qk = scal[t*4+0], p0 = scal[t*4+2], p1 = scal[t*4+3];
      float4 ob4, e4;
      float* ob = (float*)&ob4; float* e2 = (float*)&e4;
      #pragma unroll
      for (int i = 0; i < 4; ++i) {
        float ut  = Uu [t*16+vq+i];
        float ust = Uss[t*16+vq+i];
        float qfn = fmaf(fa, pq[i],  qk*ut);
        float qsn = fmaf(sa, pqs[i], qk*ust);
        ob[i] = fmaf(p0, qfn, p1*qsn);
        float pd = vreg[i] - 0.5f*(pq[i] + pqs[i]);
        e2[i] = pd*pd;
      }
      *(float4*)&OBASE[(tok0 + t)*64 + vs0 + vq] = ob4;
      *(float4*)&E2   [(tok0 + t)*64 + vs0 + vq] = e4;

      // state update: F = fa^64 F + sum_j fa^{63-j} k_j u_j^T (t acts as kd)
      float accF[4], accS[4];
      const float dF = fapow[64], dS = sapow[64];
      #pragma unroll
      for (int i = 0; i < 4; ++i) {
        accF[i] = dF * Fs [t*16+vq+i];
        accS[i] = dS * Ssl[t*16+vq+i];
      }
      #pragma unroll 4
      for (int j = 0; j < 64; ++j) {
        const float kj = Kc[j*68 + t];
        const float wf = fapow[63-j] * kj;
        const float ws = sapow[63-j] * kj;
        float4 uj  = *(const float4*)&Uu [j*16+vq];
        float4 usj = *(const float4*)&Uss[j*16+vq];
        accF[0]=fmaf(wf,uj.x,accF[0]); accF[1]=fmaf(wf,uj.y,accF[1]);
        accF[2]=fmaf(wf,uj.z,accF[2]); accF[3]=fmaf(wf,uj.w,accF[3]);
        accS[0]=fmaf(ws,usj.x,accS[0]); accS[1]=fmaf(ws,usj.y,accS[1]);
        accS[2]=fmaf(ws,usj.z,accS[2]); accS[3]=fmaf(ws,usj.w,accS[3]);
      }
      #pragma unroll
      for (int i = 0; i < 4; ++i) {
        Fs [t*16+vq+i] = accF[i];
        Ssl[t*16+vq+i] = accS[i];
      }
    }
    __syncthreads();
  }
#undef STAGE68
}

// ---------------- k4: err reduce -> ns-gate coefficient c = 0.1*u_neu
__global__ __launch_bounds__(256) void err_kernel(
    const float* __restrict__ E, float* __restrict__ CNS) {
  int row = blockIdx.x*4 + (threadIdx.x >> 6);
  int l = threadIdx.x & 63;
  float s = wsum(E[(size_t)row*64 + l]);
  if (l == 0) {
    float z = s / (1.0f + 1e-6f);          // TEMP + 1e-6
    float sg = 1.f/(1.f+expf(-z));
    CNS[row] = (sg > 0.7f) ? 0.1f : 0.f;
  }
}

// ---------------- k5: ns scan + o assembly, software-pipelined
#define BW 16
__device__ __forceinline__ void loadw(int b, int t0, int v,
    const float* __restrict__ CNS, const float* __restrict__ NU,
    const float* __restrict__ OBASE, const float* __restrict__ PW,
    float* c, float* nu, float* ob, float* p2) {
  #pragma unroll
  for (int i = 0; i < BW; ++i) {
    size_t bt = (size_t)b*SS + (t0 + i);
    c[i]  = CNS[bt];
    nu[i] = NU[bt*64 + v];
    ob[i] = OBASE[bt*64 + v];
    p2[i] = PW[bt*3 + 2];
  }
}
__device__ __forceinline__ float procw(int b, int t0, int v, float ns,
    const float* c, const float* nu, const float* ob, const float* p2,
    float* __restrict__ OB) {
  #pragma unroll
  for (int i = 0; i < BW; ++i) {
    float cn = c[i]*nu[i];
    float a  = 1.f - c[i];
    ns = fmaf(a, ns, cn);                 // ns = (1-c)*ns + c*nu
    float o = fmaf(p2[i], ns, ob[i]);
    OB[((size_t)b*SS + (t0+i))*64 + v] = o;
  }
  return ns;
}
__global__ __launch_bounds__(64) void nsout_kernel(
    const float* __restrict__ CNS, const float* __restrict__ NU,
    const float* __restrict__ OBASE, const float* __restrict__ PW,
    float* __restrict__ OB) {
  const int b = blockIdx.x, v = threadIdx.x;
  float cA[BW],nA[BW],oA[BW],pA[BW], cB[BW],nB[BW],oB[BW],pB[BW];
  loadw(b, 0, v, CNS, NU, OBASE, PW, cA, nA, oA, pA);
  float ns = 0.f;
  for (int t0 = 0; t0 < SS; t0 += 2*BW) {
    int tB = t0 + BW;
    loadw(b, tB, v, CNS, NU, OBASE, PW, cB, nB, oB, pB);
    ns = procw(b, t0, v, ns, cA, nA, oA, pA, OB);
    int tA2 = t0 + 2*BW; if (tA2 > SS - BW) tA2 = SS - BW;
    loadw(b, tA2, v, CNS, NU, OBASE, PW, cA, nA, oA, pA);
    ns = procw(b, tB, v, ns, cB, nB, oB, pB, OB);
  }
}

// ---------------- k6: fused RMSNorm + out = normed @ Wo^T
__global__ __launch_bounds__(256) void out_gemm(
    const float* __restrict__ OB, const float* __restrict__ Wo,
    const float* __restrict__ normw, float* __restrict__ out) {
  __shared__ float As[64*64];    // [k][m]
  __shared__ float Bs[64*128];   // [k][n]
  const int t  = threadIdx.x;
  const int m0 = blockIdx.y * 64;
  const int n0 = blockIdx.x * 128;
  {
    int r = t >> 2, q4 = t & 3;
    const float* src = OB + (size_t)(m0 + r)*64 + q4*16;
    float4 x0 = ld4(src), x1 = ld4(src+4), x2 = ld4(src+8), x3 = ld4(src+12);
    float ss = x0.x*x0.x+x0.y*x0.y+x0.z*x0.z+x0.w*x0.w
             + x1.x*x1.x+x1.y*x1.y+x1.z*x1.z+x1.w*x1.w
             + x2.x*x2.x+x2.y*x2.y+x2.z*x2.z+x2.w*x2.w
             + x3.x*x3.x+x3.y*x3.y+x3.z*x3.z+x3.w*x3.w;
    ss += __shfl_xor(ss, 1, 64);
    ss += __shfl_xor(ss, 2, 64);
    float rms = rsqrtf(ss * (1.f/64.f) + 1e-6f);
    const float* nw = normw + q4*16;
    float4 w0 = ld4(nw), w1 = ld4(nw+4), w2 = ld4(nw+8), w3 = ld4(nw+12);
    int kbase = q4*16;
    As[(kbase+ 0)*64+r]=x0.x*rms*w0.x; As[(kbase+ 1)*64+r]=x0.y*rms*w0.y;
    As[(kbase+ 2)*64+r]=x0.z*rms*w0.z; As[(kbase+ 3)*64+r]=x0.w*rms*w0.w;
    As[(kbase+ 4)*64+r]=x1.x*rms*w1.x; As[(kbase+ 5)*64+r]=x1.y*rms*w1.y;
    As[(kbase+ 6)*64+r]=x1.z*rms*w1.z; As[(kbase+ 7)*64+r]=x1.w*rms*w1.w;
    As[(kbase+ 8)*64+r]=x2.x*rms*w2.x; As[(kbase+ 9)*64+r]=x2.y*rms*w2.y;
    As[(kbase+10)*64+r]=x2.z*rms*w2.z; As[(kbase+11)*64+r]=x2.w*rms*w2.w;
    As[(kbase+12)*64+r]=x3.x*rms*w3.x; As[(kbase+13)*64+r]=x3.y*rms*w3.y;
    As[(kbase+14)*64+r]=x3.z*rms*w3.z; As[(kbase+15)*64+r]=x3.w*rms*w3.w;
  }
  {
    int rw = t >> 1, half = t & 1;
    const float* src = Wo + (size_t)(n0 + rw)*64 + half*32;
    #pragma unroll
    for (int j = 0; j < 8; ++j) {
      float4 w = ld4(src + j*4);
      int k = half*32 + j*4;
      Bs[(k+0)*128+rw] = w.x; Bs[(k+1)*128+rw] = w.y;
      Bs[(k+2)*128+rw] = w.z; Bs[(k+3)*128+rw] = w.w;
    }
  }
  __syncthreads();
  const int mi = t >> 5, ni = t & 31;
  float acc[8][4];
  #pragma unroll
  for (int i = 0; i < 8; ++i)
    #pragma unroll
    for (int j = 0; j < 4; ++j) acc[i][j] = 0.f;
  #pragma unroll 8
  for (int k = 0; k < 64; ++k) {
    float a[8], bv[4];
    float4 a0 = *(const float4*)&As[k*64 + mi*8];
    float4 a1 = *(const float4*)&As[k*64 + mi*8 + 4];
    float4 b0 = *(const float4*)&Bs[k*128 + ni*4];
    a[0]=a0.x; a[1]=a0.y; a[2]=a0.z; a[3]=a0.w;
    a[4]=a1.x; a[5]=a1.y; a[6]=a1.z; a[7]=a1.w;
    bv[0]=b0.x; bv[1]=b0.y; bv[2]=b0.z; bv[3]=b0.w;
    #pragma unroll
    for (int im = 0; im < 8; ++im)
      #pragma unroll
      for (int in = 0; in < 4; ++in)
        acc[im][in] = fmaf(a[im], bv[in], acc[im][in]);
  }
  #pragma unroll
  for (int im = 0; im < 8; ++im) {
    float4 o; o.x=acc[im][0]; o.y=acc[im][1]; o.z=acc[im][2]; o.w=acc[im][3];
    *(float4*)&out[(size_t)(m0 + mi*8 + im)*1024 + n0 + ni*4] = o;
  }
}

// ---------------- launcher ----------------
extern "C" void kernel_launch(void* const* d_in, const int* in_sizes, int n_in,
                              void* d_out, int out_size, void* d_ws, size_t ws_size,
                              hipStream_t stream) {
  const float* x     = (const float*)d_in[0];
  const float* Wk    = (const float*)d_in[1];
  const float* Wv    = (const float*)d_in[2];
  const float* Wq    = (const float*)d_in[3];
  const float* fap   = (const float*)d_in[4];
  const float* sap   = (const float*)d_in[5];
  const float* nm_w1 = (const float*)d_in[6];
  const float* nm_b1 = (const float*)d_in[7];
  const float* nm_w2 = (const float*)d_in[8];
  const float* nm_b2 = (const float*)d_in[9];
  const float* ir_w1 = (const float*)d_in[10];
  const float* ir_b1 = (const float*)d_in[11];
  const float* ir_w2 = (const float*)d_in[12];
  const float* ir_b2 = (const float*)d_in[13];
  const float* pw    = (const float*)d_in[14];
  const float* Wo    = (const float*)d_in[15];
  const float* normw = (const float*)d_in[16];
  float* out = (float*)d_out;
  float* ws  = (float*)d_ws;

  // workspace layout (floats)
  const size_t oW    = 0;
  const size_t oY    = oW  + (size_t)320*1024;        // Wcat
  const size_t oK    = oY  + (size_t)MM*320;          // Y (reused below)
  const size_t oV    = oK  + (size_t)MM*64;
  const size_t oQ    = oV  + (size_t)MM*64;
  const size_t oNU   = oQ  + (size_t)MM*64;
  const size_t oPW   = oNU + (size_t)MM*64;
  const size_t oSCL  = oPW + (size_t)MM*3;            // SCL8: MM*8
  const size_t oCNS  = oSCL + (size_t)MM*8;
  const size_t oOB   = oCNS + MM;                     // MM*64
  // Y region reused after post_kernel (Y dead by then): 4*MM*64 <= MM*320
  const size_t oOBASE = oY;                     // MM*64
  const size_t oE     = oY + (size_t)MM*64;     // MM*64
  const size_t oAKK   = oY + (size_t)2*MM*64;   // MM*64 = 256 chunks * 4096
  const size_t oAQK   = oY + (size_t)3*MM*64;   // MM*64

  pack_w<<<1280, 256, 0, stream>>>(Wk, Wv, Wq, ir_w1, pw, ws + oW);
  gemm1<<<dim3(128, 5), 256, 0, stream>>>(x, ws + oW, ws + oY);
  post_kernel<<<1024, 256, 0, stream>>>(ws + oY, nm_w1, nm_b1, nm_w2, nm_b2,
                                        ir_b1, ir_w2, ir_b2, sap,
                                        ws + oK, ws + oV, ws + oQ, ws + oNU,
                                        ws + oPW, ws + oSCL);
  chunkdots<<<256, 256, 0, stream>>>(ws + oK, ws + oQ, ws + oAKK, ws + oAQK);
  scan_chunked<<<32, 256, 0, stream>>>(ws + oK, ws + oQ, ws + oV, ws + oSCL,
                                       ws + oAKK, ws + oAQK, fap, sap,
                                       ws + oOBASE, ws + oE);
  err_kernel<<<4096, 256, 0, stream>>>(ws + oE, ws + oCNS);
  nsout_kernel<<<8, 64, 0, stream>>>(ws + oCNS, ws + oNU, ws + oOBASE,
                                     ws + oPW, ws + oOB);
  out_gemm<<<dim3(8, 256), 256, 0, stream>>>(ws + oOB, Wo, normw, out);
}